// Round 1
// baseline (11816.460 us; speedup 1.0000x reference)
//
#include <hip/hip_runtime.h>

#define HID 64
#define IN_DIM 34
#define NCLS 10

// ---------- helpers ----------

__device__ __forceinline__ unsigned enc_f(float f) {
    unsigned u = __float_as_uint(f);
    return (u & 0x80000000u) ? ~u : (u | 0x80000000u);
}
__device__ __forceinline__ float dec_f(unsigned u) {
    return __uint_as_float((u & 0x80000000u) ? (u & 0x7FFFFFFFu) : ~u);
}

// 34 -> 64 (relu) -> 64 MLP, register-blocked. All array indices static after
// unrolling; jb loop kept rolled (#pragma unroll 1) for icache. W reads are
// wave-uniform -> scalar loads.
__device__ __forceinline__ void mlp34_64(const float (&ea)[IN_DIM],
        const float* __restrict__ W1, const float* __restrict__ b1,
        const float* __restrict__ W2, const float* __restrict__ b2,
        float (&out)[HID]) {
    #pragma unroll
    for (int j = 0; j < HID; ++j) out[j] = b2[j];
    #pragma unroll 1
    for (int jb = 0; jb < HID; jb += 8) {
        float hb[8];
        #pragma unroll
        for (int u = 0; u < 8; ++u) hb[u] = b1[jb + u];
        #pragma unroll
        for (int k = 0; k < IN_DIM; ++k) {
            #pragma unroll
            for (int u = 0; u < 8; ++u)
                hb[u] = fmaf(ea[k], W1[k * HID + jb + u], hb[u]);
        }
        #pragma unroll
        for (int u = 0; u < 8; ++u) hb[u] = fmaxf(hb[u], 0.0f);
        #pragma unroll
        for (int u = 0; u < 8; ++u) {
            float hv = hb[u];
            #pragma unroll
            for (int j = 0; j < HID; ++j)
                out[j] = fmaf(hv, W2[(jb + u) * HID + j], out[j]);
        }
    }
}

// ---------- kernels ----------

// Per edge: assemble ea[34], accumulate loop-attr sums/counts at col,
// run MLP, scatter msg into s[col].
__global__ __launch_bounds__(256) void edge_pass(
        const int* __restrict__ ei, const int* __restrict__ ports,
        const int* __restrict__ flags, const float* __restrict__ eattr,
        const float* __restrict__ emb_port, const float* __restrict__ emb_flags,
        const float* __restrict__ W1, const float* __restrict__ b1,
        const float* __restrict__ W2, const float* __restrict__ b2,
        float* __restrict__ s, float* __restrict__ lsum, float* __restrict__ cnt,
        int E) {
    int e = blockIdx.x * blockDim.x + threadIdx.x;
    if (e >= E) return;
    int c = ei[E + e];

    float ea[IN_DIM];
    const float4* ap = (const float4*)(eattr + (size_t)e * 16);
    float4 a0 = ap[0], a1 = ap[1], a2 = ap[2], a3 = ap[3];
    ea[0]=a0.x; ea[1]=a0.y; ea[2]=a0.z; ea[3]=a0.w;
    ea[4]=a1.x; ea[5]=a1.y; ea[6]=a1.z; ea[7]=a1.w;
    ea[8]=a2.x; ea[9]=a2.y; ea[10]=a2.z; ea[11]=a2.w;
    ea[12]=a3.x; ea[13]=a3.y; ea[14]=a3.z; ea[15]=a3.w;
    int p = ports[e];
    const float4* pp = (const float4*)(emb_port + (size_t)p * 16);
    float4 p0 = pp[0], p1 = pp[1], p2 = pp[2], p3 = pp[3];
    ea[16]=p0.x; ea[17]=p0.y; ea[18]=p0.z; ea[19]=p0.w;
    ea[20]=p1.x; ea[21]=p1.y; ea[22]=p1.z; ea[23]=p1.w;
    ea[24]=p2.x; ea[25]=p2.y; ea[26]=p2.z; ea[27]=p2.w;
    ea[28]=p3.x; ea[29]=p3.y; ea[30]=p3.z; ea[31]=p3.w;
    int f = flags[e];
    float2 fl = *(const float2*)(emb_flags + (size_t)f * 2);
    ea[32]=fl.x; ea[33]=fl.y;

    float* lp = lsum + (size_t)c * IN_DIM;
    #pragma unroll
    for (int k = 0; k < IN_DIM; ++k) atomicAdd(lp + k, ea[k]);
    atomicAdd(cnt + c, 1.0f);

    float out[HID];
    mlp34_64(ea, W1, b1, W2, b2, out);

    float* sp = s + (size_t)c * HID;
    #pragma unroll
    for (int j = 0; j < HID; ++j) atomicAdd(sp + j, out[j]);
}

// Per node: self-loop msg = MLP(loop_attr), finalize s, write x1 = s/deg.
__global__ __launch_bounds__(256) void node_pass(
        const float* __restrict__ lsum, const float* __restrict__ cnt,
        const float* __restrict__ W1, const float* __restrict__ b1,
        const float* __restrict__ W2, const float* __restrict__ b2,
        float* __restrict__ s, float* __restrict__ x1, int N) {
    int n = blockIdx.x * blockDim.x + threadIdx.x;
    if (n >= N) return;
    float c = cnt[n];
    float invc = 1.0f / fmaxf(c, 1.0f);
    float ea[IN_DIM];
    const float* lp = lsum + (size_t)n * IN_DIM;
    #pragma unroll
    for (int k = 0; k < IN_DIM; ++k) ea[k] = lp[k] * invc;
    float out[HID];
    mlp34_64(ea, W1, b1, W2, b2, out);
    float invdeg = 1.0f / (c + 1.0f);
    float* sp = s + (size_t)n * HID;
    float* xp = x1 + (size_t)n * HID;
    #pragma unroll
    for (int j = 0; j < HID; ++j) {
        float t = sp[j] + out[j];
        sp[j] = t;
        xp[j] = t * invdeg;
    }
}

// Scatter x[row] into xn[col] (edge part of A). 16 threads per edge (4 dims each).
__global__ __launch_bounds__(256) void scatter_layer(
        const int* __restrict__ ei, const float* __restrict__ x,
        float* __restrict__ xn, int E) {
    int t = blockIdx.x * blockDim.x + threadIdx.x;
    if (t >= E * 16) return;
    int e = t >> 4, q = t & 15;
    int r = ei[e], c = ei[E + e];
    float4 v = *(const float4*)(x + (size_t)r * HID + q * 4);
    float* d = xn + (size_t)c * HID + q * 4;
    atomicAdd(d + 0, v.x);
    atomicAdd(d + 1, v.y);
    atomicAdd(d + 2, v.z);
    atomicAdd(d + 3, v.w);
}

// xn = (xn_scatter + x_prev (self) + s) / deg
__global__ __launch_bounds__(256) void finalize_layer(
        const float* __restrict__ xprev, const float* __restrict__ s,
        const float* __restrict__ cnt, float* __restrict__ xn, int N) {
    int t = blockIdx.x * blockDim.x + threadIdx.x;
    if (t >= N * 16) return;
    int n = t >> 4, q = t & 15;
    float invdeg = 1.0f / (cnt[n] + 1.0f);
    size_t o = (size_t)n * HID + q * 4;
    float4 a = *(const float4*)(xn + o);
    float4 b = *(const float4*)(xprev + o);
    float4 c4 = *(const float4*)(s + o);
    float4 r;
    r.x = (a.x + b.x + c4.x) * invdeg;
    r.y = (a.y + b.y + c4.y) * invdeg;
    r.z = (a.z + b.z + c4.z) * invdeg;
    r.w = (a.w + b.w + c4.w) * invdeg;
    *(float4*)(xn + o) = r;
}

__global__ __launch_bounds__(256) void pool_pass(
        const float* __restrict__ x, const int* __restrict__ batch,
        float* __restrict__ psum, unsigned* __restrict__ pmax,
        float* __restrict__ pcnt, int N) {
    int t = blockIdx.x * blockDim.x + threadIdx.x;
    if (t >= N * HID) return;
    int n = t >> 6, j = t & 63;
    int b = batch[n];
    float v = x[t];
    atomicAdd(&psum[b * HID + j], v);
    atomicMax(&pmax[b * HID + j], enc_f(v));
    if (j == 0) atomicAdd(&pcnt[b], 1.0f);
}

__global__ __launch_bounds__(64) void classifier_pass(
        const float* __restrict__ psum, const unsigned* __restrict__ pmax,
        const float* __restrict__ pcnt,
        const float* __restrict__ CW1, const float* __restrict__ Cb1,
        const float* __restrict__ CW2, const float* __restrict__ Cb2,
        float* __restrict__ out) {
    int g = blockIdx.x, j = threadIdx.x;
    __shared__ float pooled[2 * HID];
    __shared__ float hsh[HID];
    float gc = fmaxf(pcnt[g], 1.0f);
    pooled[j] = psum[g * HID + j] / gc;
    pooled[HID + j] = dec_f(pmax[g * HID + j]);
    __syncthreads();
    float acc = Cb1[j];
    #pragma unroll 8
    for (int k = 0; k < 2 * HID; ++k) acc = fmaf(pooled[k], CW1[k * HID + j], acc);
    hsh[j] = fmaxf(acc, 0.0f);
    __syncthreads();
    if (j < NCLS) {
        float o = Cb2[j];
        #pragma unroll 8
        for (int k = 0; k < HID; ++k) o = fmaf(hsh[k], CW2[k * NCLS + j], o);
        out[g * NCLS + j] = o;
    }
}

// ---------- launch ----------

extern "C" void kernel_launch(void* const* d_in, const int* in_sizes, int n_in,
                              void* d_out, int out_size, void* d_ws, size_t ws_size,
                              hipStream_t stream) {
    const int*   ei        = (const int*)d_in[0];
    const int*   ports     = (const int*)d_in[1];
    const int*   flags     = (const int*)d_in[2];
    const float* eattr     = (const float*)d_in[3];
    const int*   batch     = (const int*)d_in[4];
    const float* emb_port  = (const float*)d_in[5];
    const float* emb_flags = (const float*)d_in[6];
    const float* W1  = (const float*)d_in[7];
    const float* b1  = (const float*)d_in[8];
    const float* W2  = (const float*)d_in[9];
    const float* b2  = (const float*)d_in[10];
    const float* CW1 = (const float*)d_in[11];
    const float* Cb1 = (const float*)d_in[12];
    const float* CW2 = (const float*)d_in[13];
    const float* Cb2 = (const float*)d_in[14];
    float* outp = (float*)d_out;

    const int E = in_sizes[0] / 2;
    const int N = in_sizes[4];
    const int B = out_size / NCLS;

    // workspace layout (floats); zeroed region first, xA (fully written) last
    float* ws   = (float*)d_ws;
    float* s    = ws;                         // N*64
    float* lsum = s    + (size_t)N * HID;     // N*34
    float* cnt  = lsum + (size_t)N * IN_DIM;  // N
    float* xB   = cnt  + (size_t)N;           // N*64
    float* xC   = xB   + (size_t)N * HID;     // N*64
    float* psum = xC   + (size_t)N * HID;     // B*64
    unsigned* pmax = (unsigned*)(psum + (size_t)B * HID); // B*64
    float* pcnt = (float*)(pmax + (size_t)B * HID);       // B
    float* xA   = pcnt + B;                   // N*64 (not zeroed)

    size_t zero_bytes = (size_t)((char*)xA - (char*)ws);
    hipMemsetAsync(d_ws, 0, zero_bytes, stream);

    edge_pass<<<(E + 255) / 256, 256, 0, stream>>>(
        ei, ports, flags, eattr, emb_port, emb_flags,
        W1, b1, W2, b2, s, lsum, cnt, E);

    node_pass<<<(N + 255) / 256, 256, 0, stream>>>(
        lsum, cnt, W1, b1, W2, b2, s, xA, N);

    // layer 2
    scatter_layer<<<(E * 16 + 255) / 256, 256, 0, stream>>>(ei, xA, xB, E);
    finalize_layer<<<(N * 16 + 255) / 256, 256, 0, stream>>>(xA, s, cnt, xB, N);

    // layer 3
    scatter_layer<<<(E * 16 + 255) / 256, 256, 0, stream>>>(ei, xB, xC, E);
    finalize_layer<<<(N * 16 + 255) / 256, 256, 0, stream>>>(xB, s, cnt, xC, N);

    pool_pass<<<(N * HID + 255) / 256, 256, 0, stream>>>(xC, batch, psum, pmax, pcnt, N);

    classifier_pass<<<B, 64, 0, stream>>>(psum, pmax, pcnt, CW1, Cb1, CW2, Cb2, outp);
}

// Round 3
// 1476.717 us; speedup vs baseline: 8.0018x; 8.0018x over previous
//
#include <hip/hip_runtime.h>

#define HID 64
#define IN_DIM 34
#define NCLS 10

// ---------- helpers ----------

__device__ __forceinline__ unsigned enc_f(float f) {
    unsigned u = __float_as_uint(f);
    return (u & 0x80000000u) ? ~u : (u | 0x80000000u);
}
__device__ __forceinline__ float dec_f(unsigned u) {
    return __uint_as_float((u & 0x80000000u) ? (u & 0x7FFFFFFFu) : ~u);
}

// 34 -> 64 (relu) -> 64 MLP, register-blocked (thread-per-row version, used
// only for the 100k self-loop rows). Weights wave-uniform -> scalar loads.
__device__ __forceinline__ void mlp34_64(const float (&ea)[IN_DIM],
        const float* __restrict__ W1, const float* __restrict__ b1,
        const float* __restrict__ W2, const float* __restrict__ b2,
        float (&out)[HID]) {
    #pragma unroll
    for (int j = 0; j < HID; ++j) out[j] = b2[j];
    #pragma unroll 1
    for (int jb = 0; jb < HID; jb += 8) {
        float hb[8];
        #pragma unroll
        for (int u = 0; u < 8; ++u) hb[u] = b1[jb + u];
        #pragma unroll
        for (int k = 0; k < IN_DIM; ++k) {
            #pragma unroll
            for (int u = 0; u < 8; ++u)
                hb[u] = fmaf(ea[k], W1[k * HID + jb + u], hb[u]);
        }
        #pragma unroll
        for (int u = 0; u < 8; ++u) hb[u] = fmaxf(hb[u], 0.0f);
        #pragma unroll
        for (int u = 0; u < 8; ++u) {
            float hv = hb[u];
            #pragma unroll
            for (int j = 0; j < HID; ++j)
                out[j] = fmaf(hv, W2[(jb + u) * HID + j], out[j]);
        }
    }
}

// ---------- CSR build ----------

__global__ __launch_bounds__(256) void hist_pass(
        const int* __restrict__ ei, int* __restrict__ hist, int E) {
    int e = blockIdx.x * blockDim.x + threadIdx.x;
    if (e >= E) return;
    atomicAdd(&hist[ei[E + e]], 1);
}

__global__ __launch_bounds__(256) void scan1(
        const int* __restrict__ hist, int* __restrict__ loc,
        int* __restrict__ part, int N) {
    __shared__ int sh[256];
    int tid = threadIdx.x;
    int i = blockIdx.x * 256 + tid;
    int v = (i < N) ? hist[i] : 0;
    sh[tid] = v;
    __syncthreads();
    for (int d = 1; d < 256; d <<= 1) {
        int t = (tid >= d) ? sh[tid - d] : 0;
        __syncthreads();
        sh[tid] += t;
        __syncthreads();
    }
    if (i < N) loc[i] = sh[tid] - v;          // exclusive
    if (tid == 255) part[blockIdx.x] = sh[255];
}

__global__ __launch_bounds__(512) void scan2(int* __restrict__ part, int NB) {
    __shared__ int sh[512];
    int t = threadIdx.x;
    int v = (t < NB) ? part[t] : 0;
    sh[t] = v;
    __syncthreads();
    for (int d = 1; d < 512; d <<= 1) {
        int u = (t >= d) ? sh[t - d] : 0;
        __syncthreads();
        sh[t] += u;
        __syncthreads();
    }
    if (t < NB) part[t] = sh[t] - v;          // exclusive
}

__global__ __launch_bounds__(256) void scan3(
        const int* __restrict__ loc, const int* __restrict__ part,
        int* __restrict__ offs, int* __restrict__ cursor, int N) {
    int i = blockIdx.x * 256 + threadIdx.x;
    if (i >= N) return;
    int o = loc[i] + part[blockIdx.x];
    offs[i] = o;
    cursor[i] = o;
}

// bucket edges by col: eid_sorted / src_sorted
__global__ __launch_bounds__(256) void sort_pass(
        const int* __restrict__ ei, int* __restrict__ cursor,
        int* __restrict__ eid_sorted, int* __restrict__ src_sorted, int E) {
    int e = blockIdx.x * blockDim.x + threadIdx.x;
    if (e >= E) return;
    int c = ei[E + e];
    int pos = atomicAdd(&cursor[c], 1);
    eid_sorted[pos] = e;
    src_sorted[pos] = ei[e];
}

// ---------- fused edge-MLP + aggregation ----------
// One 64-thread block per node; lane j owns output channel j.
// s[n][j] = sum over incident edges of MLP(ea_e)[j]; lsum[n][k] = sum ea[k].
// No atomics, no materialized msg.
__global__ __launch_bounds__(64) void node_edge_pass(
        const int* __restrict__ offs, const int* __restrict__ hist,
        const int* __restrict__ eid_sorted,
        const int* __restrict__ ports, const int* __restrict__ flags,
        const float* __restrict__ eattr,
        const float* __restrict__ emb_port, const float* __restrict__ emb_flags,
        const float* __restrict__ W1, const float* __restrict__ b1,
        const float* __restrict__ W2, const float* __restrict__ b2,
        float* __restrict__ s, float* __restrict__ lsum, int N) {
    int n = blockIdx.x;
    int lane = threadIdx.x;
    int off = offs[n];
    int d = hist[n];

    __shared__ float ea_sh[64];   // 34 valid + zero pad (lanes 34..63 write 0)
    __shared__ float h_sh[64];

    // weight column j in registers; W1 col padded to 36 with zeros so the
    // inner product can run as 9 clean float4 broadcasts.
    float w1c[36];
    #pragma unroll
    for (int k = 0; k < IN_DIM; ++k) w1c[k] = W1[k * HID + lane];
    w1c[34] = 0.0f; w1c[35] = 0.0f;
    float w2c[HID];
    #pragma unroll
    for (int u = 0; u < HID; ++u) w2c[u] = W2[u * HID + lane];
    float b1j = b1[lane];
    float b2j = b2[lane];

    float sacc = 0.0f;   // sum over edges of out_j (minus the b2 term)
    float asum = 0.0f;   // lane k < 34: sum over edges of ea[k]

    for (int i = 0; i < d; ++i) {
        int eid = eid_sorted[off + i];          // block-uniform -> scalar load
        float v = 0.0f;
        if (lane < 16)      v = eattr[(size_t)eid * 16 + lane];
        else if (lane < 32) v = emb_port[(size_t)ports[eid] * 16 + (lane - 16)];
        else if (lane < 34) v = emb_flags[(size_t)flags[eid] * 2 + (lane - 32)];
        asum += v;
        ea_sh[lane] = v;
        __syncthreads();
        float h = b1j;
        #pragma unroll
        for (int k4 = 0; k4 < 9; ++k4) {
            float4 e4 = *(const float4*)&ea_sh[k4 * 4];   // broadcast b128
            h = fmaf(e4.x, w1c[4 * k4 + 0], h);
            h = fmaf(e4.y, w1c[4 * k4 + 1], h);
            h = fmaf(e4.z, w1c[4 * k4 + 2], h);
            h = fmaf(e4.w, w1c[4 * k4 + 3], h);
        }
        h = fmaxf(h, 0.0f);
        h_sh[lane] = h;
        __syncthreads();
        float o = 0.0f;
        #pragma unroll
        for (int u4 = 0; u4 < 16; ++u4) {
            float4 h4 = *(const float4*)&h_sh[u4 * 4];    // broadcast b128
            o = fmaf(h4.x, w2c[4 * u4 + 0], o);
            o = fmaf(h4.y, w2c[4 * u4 + 1], o);
            o = fmaf(h4.z, w2c[4 * u4 + 2], o);
            o = fmaf(h4.w, w2c[4 * u4 + 3], o);
        }
        sacc += o;
    }

    s[(size_t)n * HID + lane] = sacc + (float)d * b2j;
    if (lane < IN_DIM) lsum[(size_t)n * IN_DIM + lane] = asum;
}

// Thread per node: self-loop MLP, finalize s, write x1 = s/deg.
__global__ __launch_bounds__(256) void node_mlp(
        const float* __restrict__ lsum, const int* __restrict__ hist,
        const float* __restrict__ W1, const float* __restrict__ b1,
        const float* __restrict__ W2, const float* __restrict__ b2,
        float* __restrict__ s, float* __restrict__ x1, int N) {
    int n = blockIdx.x * blockDim.x + threadIdx.x;
    if (n >= N) return;
    int c = hist[n];
    float invc = 1.0f / fmaxf((float)c, 1.0f);
    float ea[IN_DIM];
    const float* lp = lsum + (size_t)n * IN_DIM;
    #pragma unroll
    for (int k = 0; k < IN_DIM; ++k) ea[k] = lp[k] * invc;
    float out[HID];
    mlp34_64(ea, W1, b1, W2, b2, out);
    float invdeg = 1.0f / (float)(c + 1);
    float* sp = s + (size_t)n * HID;
    float* xp = x1 + (size_t)n * HID;
    #pragma unroll
    for (int j = 0; j < HID; ++j) {
        float t = sp[j] + out[j];
        sp[j] = t;
        xp[j] = t * invdeg;
    }
}

// Wave per node: xn[n] = (sum_{incoming} x[src] + x[n] + s[n]) / deg
__global__ __launch_bounds__(256) void gather_layer(
        const int* __restrict__ offs, const int* __restrict__ hist,
        const int* __restrict__ src_sorted, const float* __restrict__ x,
        const float* __restrict__ s, float* __restrict__ xn, int N) {
    int wid = (blockIdx.x * blockDim.x + threadIdx.x) >> 6;
    int lane = threadIdx.x & 63;
    if (wid >= N) return;
    int off = offs[wid], d = hist[wid];
    float acc = x[(size_t)wid * HID + lane] + s[(size_t)wid * HID + lane];
    for (int i = 0; i < d; ++i) {
        int r = src_sorted[off + i];
        acc += x[(size_t)r * HID + lane];
    }
    xn[(size_t)wid * HID + lane] = acc / (float)(d + 1);
}

// Wave per 64-node chunk; batch[] is sorted so flushes are rare.
__global__ __launch_bounds__(256) void pool_pass(
        const float* __restrict__ x, const int* __restrict__ batch,
        float* __restrict__ psum, unsigned* __restrict__ pmax,
        float* __restrict__ pcnt, int N) {
    const int CHUNK = 64;
    int wid = (blockIdx.x * blockDim.x + threadIdx.x) >> 6;
    int lane = threadIdx.x & 63;
    int n0 = wid * CHUNK;
    if (n0 >= N) return;
    int n1 = min(n0 + CHUNK, N);
    int gcur = batch[n0];
    float sum = 0.0f, mx = -3.402823e38f;
    int cnt = 0;
    for (int n = n0; n < n1; ++n) {
        int g = batch[n];
        if (g != gcur) {
            atomicAdd(&psum[gcur * HID + lane], sum);
            atomicMax(&pmax[gcur * HID + lane], enc_f(mx));
            if (lane == 0) atomicAdd(&pcnt[gcur], (float)cnt);
            gcur = g; sum = 0.0f; mx = -3.402823e38f; cnt = 0;
        }
        float v = x[(size_t)n * HID + lane];
        sum += v;
        mx = fmaxf(mx, v);
        ++cnt;
    }
    atomicAdd(&psum[gcur * HID + lane], sum);
    atomicMax(&pmax[gcur * HID + lane], enc_f(mx));
    if (lane == 0) atomicAdd(&pcnt[gcur], (float)cnt);
}

__global__ __launch_bounds__(64) void classifier_pass(
        const float* __restrict__ psum, const unsigned* __restrict__ pmax,
        const float* __restrict__ pcnt,
        const float* __restrict__ CW1, const float* __restrict__ Cb1,
        const float* __restrict__ CW2, const float* __restrict__ Cb2,
        float* __restrict__ out) {
    int g = blockIdx.x, j = threadIdx.x;
    __shared__ float pooled[2 * HID];
    __shared__ float hsh[HID];
    float gc = fmaxf(pcnt[g], 1.0f);
    pooled[j] = psum[g * HID + j] / gc;
    pooled[HID + j] = dec_f(pmax[g * HID + j]);
    __syncthreads();
    float acc = Cb1[j];
    #pragma unroll 8
    for (int k = 0; k < 2 * HID; ++k) acc = fmaf(pooled[k], CW1[k * HID + j], acc);
    hsh[j] = fmaxf(acc, 0.0f);
    __syncthreads();
    if (j < NCLS) {
        float o = Cb2[j];
        #pragma unroll 8
        for (int k = 0; k < HID; ++k) o = fmaf(hsh[k], CW2[k * NCLS + j], o);
        out[g * NCLS + j] = o;
    }
}

// ---------- launch ----------

extern "C" void kernel_launch(void* const* d_in, const int* in_sizes, int n_in,
                              void* d_out, int out_size, void* d_ws, size_t ws_size,
                              hipStream_t stream) {
    const int*   ei        = (const int*)d_in[0];
    const int*   ports     = (const int*)d_in[1];
    const int*   flags     = (const int*)d_in[2];
    const float* eattr     = (const float*)d_in[3];
    const int*   batch     = (const int*)d_in[4];
    const float* emb_port  = (const float*)d_in[5];
    const float* emb_flags = (const float*)d_in[6];
    const float* W1  = (const float*)d_in[7];
    const float* b1  = (const float*)d_in[8];
    const float* W2  = (const float*)d_in[9];
    const float* b2  = (const float*)d_in[10];
    const float* CW1 = (const float*)d_in[11];
    const float* Cb1 = (const float*)d_in[12];
    const float* CW2 = (const float*)d_in[13];
    const float* Cb2 = (const float*)d_in[14];
    float* outp = (float*)d_out;

    const int E = in_sizes[0] / 2;
    const int N = in_sizes[4];
    const int B = out_size / NCLS;
    const int NB = (N + 255) / 256;     // scan blocks (must be <= 512)

    // ---- workspace layout (~105 MB total; proven-safe budget >= 142 MB) ----
    char* w = (char*)d_ws;
    float* s          = (float*)w;      w += (size_t)N * HID * 4;     // 25.6M
    float* xA         = (float*)w;      w += (size_t)N * HID * 4;     // 25.6M
    float* xB         = (float*)w;      w += (size_t)N * HID * 4;     // 25.6M
    float* lsum       = (float*)w;      w += (size_t)N * IN_DIM * 4;  // 13.6M
    int*   eid_sorted = (int*)w;        w += (size_t)E * 4;           // 6.4M
    int*   src_sorted = (int*)w;        w += (size_t)E * 4;           // 6.4M
    int*   offs       = (int*)w;        w += (size_t)N * 4;
    int*   cursor     = (int*)w;        w += (size_t)N * 4;
    int*   loc        = (int*)w;        w += (size_t)N * 4;
    int*   part       = (int*)w;        w += 512 * 4;
    // zero region (single memset): hist, psum, pmax, pcnt
    char* zero_base = w;
    int*      hist  = (int*)w;          w += (size_t)N * 4;
    float*    psum  = (float*)w;        w += (size_t)B * HID * 4;
    unsigned* pmax  = (unsigned*)w;     w += (size_t)B * HID * 4;
    float*    pcnt  = (float*)w;        w += (size_t)B * 4;
    size_t zero_bytes = (size_t)(w - zero_base);

    hipMemsetAsync(zero_base, 0, zero_bytes, stream);

    // CSR build + bucket sort by col
    hist_pass<<<(E + 255) / 256, 256, 0, stream>>>(ei, hist, E);
    scan1<<<NB, 256, 0, stream>>>(hist, loc, part, N);
    scan2<<<1, 512, 0, stream>>>(part, NB);
    scan3<<<NB, 256, 0, stream>>>(loc, part, offs, cursor, N);
    sort_pass<<<(E + 255) / 256, 256, 0, stream>>>(ei, cursor, eid_sorted, src_sorted, E);

    // fused edge MLP + aggregation (s, lsum), then self-loop MLP -> x1
    node_edge_pass<<<N, 64, 0, stream>>>(
        offs, hist, eid_sorted, ports, flags, eattr, emb_port, emb_flags,
        W1, b1, W2, b2, s, lsum, N);
    node_mlp<<<(N + 255) / 256, 256, 0, stream>>>(
        lsum, hist, W1, b1, W2, b2, s, xA, N);

    // layers 2 and 3
    gather_layer<<<(N * 64 + 255) / 256, 256, 0, stream>>>(
        offs, hist, src_sorted, xA, s, xB, N);
    gather_layer<<<(N * 64 + 255) / 256, 256, 0, stream>>>(
        offs, hist, src_sorted, xB, s, xA, N);

    // pooling + classifier
    pool_pass<<<((N + 63) / 64 * 64 + 255) / 256, 256, 0, stream>>>(
        xA, batch, psum, pmax, pcnt, N);
    classifier_pass<<<B, 64, 0, stream>>>(psum, pmax, pcnt, CW1, Cb1, CW2, Cb2, outp);
}

// Round 4
// 1088.189 us; speedup vs baseline: 10.8588x; 1.3570x over previous
//
#include <hip/hip_runtime.h>

#define HID 64
#define IN_DIM 34
#define NCLS 10

// ---------- helpers ----------

__device__ __forceinline__ unsigned enc_f(float f) {
    unsigned u = __float_as_uint(f);
    return (u & 0x80000000u) ? ~u : (u | 0x80000000u);
}
__device__ __forceinline__ float dec_f(unsigned u) {
    return __uint_as_float((u & 0x80000000u) ? (u & 0x7FFFFFFFu) : ~u);
}

// 34 -> 64 (relu) -> 64 MLP, register-blocked. Weight indices wave-uniform
// -> scalar loads. Includes b1/b2.
__device__ __forceinline__ void mlp34_64(const float (&ea)[IN_DIM],
        const float* __restrict__ W1, const float* __restrict__ b1,
        const float* __restrict__ W2, const float* __restrict__ b2,
        float (&out)[HID]) {
    #pragma unroll
    for (int j = 0; j < HID; ++j) out[j] = b2[j];
    #pragma unroll 1
    for (int jb = 0; jb < HID; jb += 8) {
        float hb[8];
        #pragma unroll
        for (int u = 0; u < 8; ++u) hb[u] = b1[jb + u];
        #pragma unroll
        for (int k = 0; k < IN_DIM; ++k) {
            #pragma unroll
            for (int u = 0; u < 8; ++u)
                hb[u] = fmaf(ea[k], W1[k * HID + jb + u], hb[u]);
        }
        #pragma unroll
        for (int u = 0; u < 8; ++u) hb[u] = fmaxf(hb[u], 0.0f);
        #pragma unroll
        for (int u = 0; u < 8; ++u) {
            float hv = hb[u];
            #pragma unroll
            for (int j = 0; j < HID; ++j)
                out[j] = fmaf(hv, W2[(jb + u) * HID + j], out[j]);
        }
    }
}

// ---------- CSR build ----------

__global__ __launch_bounds__(256) void hist_pass(
        const int* __restrict__ ei, int* __restrict__ hist, int E) {
    int e = blockIdx.x * blockDim.x + threadIdx.x;
    if (e >= E) return;
    atomicAdd(&hist[ei[E + e]], 1);
}

__global__ __launch_bounds__(256) void scan1(
        const int* __restrict__ hist, int* __restrict__ loc,
        int* __restrict__ part, int N) {
    __shared__ int sh[256];
    int tid = threadIdx.x;
    int i = blockIdx.x * 256 + tid;
    int v = (i < N) ? hist[i] : 0;
    sh[tid] = v;
    __syncthreads();
    for (int d = 1; d < 256; d <<= 1) {
        int t = (tid >= d) ? sh[tid - d] : 0;
        __syncthreads();
        sh[tid] += t;
        __syncthreads();
    }
    if (i < N) loc[i] = sh[tid] - v;          // exclusive
    if (tid == 255) part[blockIdx.x] = sh[255];
}

__global__ __launch_bounds__(512) void scan2(int* __restrict__ part, int NB) {
    __shared__ int sh[512];
    int t = threadIdx.x;
    int v = (t < NB) ? part[t] : 0;
    sh[t] = v;
    __syncthreads();
    for (int d = 1; d < 512; d <<= 1) {
        int u = (t >= d) ? sh[t - d] : 0;
        __syncthreads();
        sh[t] += u;
        __syncthreads();
    }
    if (t < NB) part[t] = sh[t] - v;          // exclusive
}

__global__ __launch_bounds__(256) void scan3(
        const int* __restrict__ loc, const int* __restrict__ part,
        int* __restrict__ offs, int* __restrict__ cursor, int N) {
    int i = blockIdx.x * 256 + threadIdx.x;
    if (i >= N) return;
    int o = loc[i] + part[blockIdx.x];
    offs[i] = o;
    cursor[i] = o;
}

// bucket edges by col; also pre-gather packed (port | flag<<16) so the hot
// kernel reads everything except eattr coalesced.
__global__ __launch_bounds__(256) void sort_pass(
        const int* __restrict__ ei, const int* __restrict__ ports,
        const int* __restrict__ flags, int* __restrict__ cursor,
        int* __restrict__ eid_sorted, int* __restrict__ src_sorted,
        int* __restrict__ col_sorted, unsigned* __restrict__ pf_sorted, int E) {
    int e = blockIdx.x * blockDim.x + threadIdx.x;
    if (e >= E) return;
    int c = ei[E + e];
    int pos = atomicAdd(&cursor[c], 1);
    eid_sorted[pos] = e;
    src_sorted[pos] = ei[e];
    col_sorted[pos] = c;
    pf_sorted[pos] = (unsigned)ports[e] | ((unsigned)flags[e] << 16);
}

// ---------- edge-parallel MLP + block segmented reduction ----------
// 128 threads/block, thread per sorted edge. LDS tile 128x64 (XOR-swizzled
// float4 chunks: write conflict-free, read conflict-free). Each wave reduces
// its own 64 rows by col-runs -> one coalesced atomicAdd per segment.
__global__ __launch_bounds__(128) void edge_mlp_reduce(
        const int* __restrict__ eid_sorted, const int* __restrict__ col_sorted,
        const unsigned* __restrict__ pf_sorted, const float* __restrict__ eattr,
        const float* __restrict__ emb_port, const float* __restrict__ emb_flags,
        const float* __restrict__ W1, const float* __restrict__ b1,
        const float* __restrict__ W2, const float* __restrict__ b2,
        float* __restrict__ s, float* __restrict__ lsum, int E) {
    __shared__ float red_sh[128 * 64];
    __shared__ int col_sh[128];

    int tid = threadIdx.x;
    int lane = tid & 63;
    int wv = tid >> 6;
    int idx = blockIdx.x * 128 + tid;
    bool valid = idx < E;

    col_sh[tid] = valid ? col_sorted[idx] : -1;

    float ea[IN_DIM];
    #pragma unroll
    for (int k = 0; k < IN_DIM; ++k) ea[k] = 0.0f;
    if (valid) {
        int eid = eid_sorted[idx];
        const float4* ap = (const float4*)(eattr + (size_t)eid * 16);
        float4 a0 = ap[0], a1 = ap[1], a2 = ap[2], a3 = ap[3];
        ea[0]=a0.x; ea[1]=a0.y; ea[2]=a0.z; ea[3]=a0.w;
        ea[4]=a1.x; ea[5]=a1.y; ea[6]=a1.z; ea[7]=a1.w;
        ea[8]=a2.x; ea[9]=a2.y; ea[10]=a2.z; ea[11]=a2.w;
        ea[12]=a3.x; ea[13]=a3.y; ea[14]=a3.z; ea[15]=a3.w;
        unsigned pf = pf_sorted[idx];
        int p = (int)(pf & 0xFFFFu);
        int f = (int)(pf >> 16);
        const float4* pp = (const float4*)(emb_port + (size_t)p * 16);
        float4 p0 = pp[0], p1 = pp[1], p2 = pp[2], p3 = pp[3];
        ea[16]=p0.x; ea[17]=p0.y; ea[18]=p0.z; ea[19]=p0.w;
        ea[20]=p1.x; ea[21]=p1.y; ea[22]=p1.z; ea[23]=p1.w;
        ea[24]=p2.x; ea[25]=p2.y; ea[26]=p2.z; ea[27]=p2.w;
        ea[28]=p3.x; ea[29]=p3.y; ea[30]=p3.z; ea[31]=p3.w;
        float2 fl = *(const float2*)(emb_flags + (size_t)f * 2);
        ea[32]=fl.x; ea[33]=fl.y;
    }

    float out[HID];
    mlp34_64(ea, W1, b1, W2, b2, out);

    // ---- phase 1: msg reduction ----
    #pragma unroll
    for (int c = 0; c < 16; ++c) {
        int slot = c ^ (tid & 15);
        float4 v;
        if (valid) { v.x = out[4*c]; v.y = out[4*c+1]; v.z = out[4*c+2]; v.w = out[4*c+3]; }
        else       { v.x = v.y = v.z = v.w = 0.0f; }
        *(float4*)&red_sh[tid * 64 + slot * 4] = v;
    }
    __syncthreads();
    {
        int r0 = wv * 64;
        float acc = 0.0f;
        int cur = col_sh[r0];
        for (int r = r0; r < r0 + 64; ++r) {
            int cr = col_sh[r];
            if (cr != cur) {
                if (cur >= 0) atomicAdd(&s[(size_t)cur * HID + lane], acc);
                acc = 0.0f;
                cur = cr;
            }
            int slot = (lane >> 2) ^ (r & 15);
            acc += red_sh[r * 64 + slot * 4 + (lane & 3)];
        }
        if (cur >= 0) atomicAdd(&s[(size_t)cur * HID + lane], acc);
    }
    __syncthreads();

    // ---- phase 2: loop-attr (lsum) reduction, reusing red_sh ----
    #pragma unroll
    for (int c = 0; c < 9; ++c) {
        int slot = c ^ (tid & 15);
        float4 v;
        v.x = (4*c   < IN_DIM && valid) ? ea[4*c]   : 0.0f;
        v.y = (4*c+1 < IN_DIM && valid) ? ea[4*c+1] : 0.0f;
        v.z = (4*c+2 < IN_DIM && valid) ? ea[4*c+2] : 0.0f;
        v.w = (4*c+3 < IN_DIM && valid) ? ea[4*c+3] : 0.0f;
        *(float4*)&red_sh[tid * 64 + slot * 4] = v;
    }
    __syncthreads();
    {
        int r0 = wv * 64;
        float acc = 0.0f;
        int cur = col_sh[r0];
        for (int r = r0; r < r0 + 64; ++r) {
            int cr = col_sh[r];
            if (cr != cur) {
                if (cur >= 0 && lane < IN_DIM)
                    atomicAdd(&lsum[(size_t)cur * IN_DIM + lane], acc);
                acc = 0.0f;
                cur = cr;
            }
            if (lane < 36) {
                int slot = (lane >> 2) ^ (r & 15);
                acc += red_sh[r * 64 + slot * 4 + (lane & 3)];
            }
        }
        if (cur >= 0 && lane < IN_DIM)
            atomicAdd(&lsum[(size_t)cur * IN_DIM + lane], acc);
    }
}

// Thread per node: self-loop MLP, finalize s, write x1 = s/deg.
__global__ __launch_bounds__(256) void node_mlp(
        const float* __restrict__ lsum, const int* __restrict__ hist,
        const float* __restrict__ W1, const float* __restrict__ b1,
        const float* __restrict__ W2, const float* __restrict__ b2,
        float* __restrict__ s, float* __restrict__ x1, int N) {
    int n = blockIdx.x * blockDim.x + threadIdx.x;
    if (n >= N) return;
    int c = hist[n];
    float invc = 1.0f / fmaxf((float)c, 1.0f);
    float ea[IN_DIM];
    const float* lp = lsum + (size_t)n * IN_DIM;
    #pragma unroll
    for (int k = 0; k < IN_DIM; ++k) ea[k] = lp[k] * invc;
    float out[HID];
    mlp34_64(ea, W1, b1, W2, b2, out);
    float invdeg = 1.0f / (float)(c + 1);
    float* sp = s + (size_t)n * HID;
    float* xp = x1 + (size_t)n * HID;
    #pragma unroll
    for (int j = 0; j < HID; ++j) {
        float t = sp[j] + out[j];
        sp[j] = t;
        xp[j] = t * invdeg;
    }
}

// 4 waves/block, wave per node, 4-wide pipelined gather:
// xn[n] = (sum_{incoming} x[src] + x[n] + s[n]) / deg
__global__ __launch_bounds__(256) void gather_layer(
        const int* __restrict__ offs, const int* __restrict__ hist,
        const int* __restrict__ src_sorted, const float* __restrict__ x,
        const float* __restrict__ s, float* __restrict__ xn, int N) {
    int wid = (blockIdx.x * blockDim.x + threadIdx.x) >> 6;
    int lane = threadIdx.x & 63;
    if (wid >= N) return;
    int off = offs[wid], d = hist[wid];
    float acc = x[(size_t)wid * HID + lane] + s[(size_t)wid * HID + lane];
    int i = 0;
    for (; i + 4 <= d; i += 4) {
        int r0 = src_sorted[off + i];
        int r1 = src_sorted[off + i + 1];
        int r2 = src_sorted[off + i + 2];
        int r3 = src_sorted[off + i + 3];
        float v0 = x[(size_t)r0 * HID + lane];
        float v1 = x[(size_t)r1 * HID + lane];
        float v2 = x[(size_t)r2 * HID + lane];
        float v3 = x[(size_t)r3 * HID + lane];
        acc += v0 + v1 + v2 + v3;
    }
    for (; i < d; ++i) {
        int r = src_sorted[off + i];
        acc += x[(size_t)r * HID + lane];
    }
    xn[(size_t)wid * HID + lane] = acc / (float)(d + 1);
}

// Wave per 64-node chunk; batch[] is sorted so flushes are rare.
__global__ __launch_bounds__(256) void pool_pass(
        const float* __restrict__ x, const int* __restrict__ batch,
        float* __restrict__ psum, unsigned* __restrict__ pmax,
        float* __restrict__ pcnt, int N) {
    const int CHUNK = 64;
    int wid = (blockIdx.x * blockDim.x + threadIdx.x) >> 6;
    int lane = threadIdx.x & 63;
    int n0 = wid * CHUNK;
    if (n0 >= N) return;
    int n1 = min(n0 + CHUNK, N);
    int gcur = batch[n0];
    float sum = 0.0f, mx = -3.402823e38f;
    int cnt = 0;
    for (int n = n0; n < n1; ++n) {
        int g = batch[n];
        if (g != gcur) {
            atomicAdd(&psum[gcur * HID + lane], sum);
            atomicMax(&pmax[gcur * HID + lane], enc_f(mx));
            if (lane == 0) atomicAdd(&pcnt[gcur], (float)cnt);
            gcur = g; sum = 0.0f; mx = -3.402823e38f; cnt = 0;
        }
        float v = x[(size_t)n * HID + lane];
        sum += v;
        mx = fmaxf(mx, v);
        ++cnt;
    }
    atomicAdd(&psum[gcur * HID + lane], sum);
    atomicMax(&pmax[gcur * HID + lane], enc_f(mx));
    if (lane == 0) atomicAdd(&pcnt[gcur], (float)cnt);
}

__global__ __launch_bounds__(64) void classifier_pass(
        const float* __restrict__ psum, const unsigned* __restrict__ pmax,
        const float* __restrict__ pcnt,
        const float* __restrict__ CW1, const float* __restrict__ Cb1,
        const float* __restrict__ CW2, const float* __restrict__ Cb2,
        float* __restrict__ out) {
    int g = blockIdx.x, j = threadIdx.x;
    __shared__ float pooled[2 * HID];
    __shared__ float hsh[HID];
    float gc = fmaxf(pcnt[g], 1.0f);
    pooled[j] = psum[g * HID + j] / gc;
    pooled[HID + j] = dec_f(pmax[g * HID + j]);
    __syncthreads();
    float acc = Cb1[j];
    #pragma unroll 8
    for (int k = 0; k < 2 * HID; ++k) acc = fmaf(pooled[k], CW1[k * HID + j], acc);
    hsh[j] = fmaxf(acc, 0.0f);
    __syncthreads();
    if (j < NCLS) {
        float o = Cb2[j];
        #pragma unroll 8
        for (int k = 0; k < HID; ++k) o = fmaf(hsh[k], CW2[k * NCLS + j], o);
        out[g * NCLS + j] = o;
    }
}

// ---------- launch ----------

extern "C" void kernel_launch(void* const* d_in, const int* in_sizes, int n_in,
                              void* d_out, int out_size, void* d_ws, size_t ws_size,
                              hipStream_t stream) {
    const int*   ei        = (const int*)d_in[0];
    const int*   ports     = (const int*)d_in[1];
    const int*   flags     = (const int*)d_in[2];
    const float* eattr     = (const float*)d_in[3];
    const int*   batch     = (const int*)d_in[4];
    const float* emb_port  = (const float*)d_in[5];
    const float* emb_flags = (const float*)d_in[6];
    const float* W1  = (const float*)d_in[7];
    const float* b1  = (const float*)d_in[8];
    const float* W2  = (const float*)d_in[9];
    const float* b2  = (const float*)d_in[10];
    const float* CW1 = (const float*)d_in[11];
    const float* Cb1 = (const float*)d_in[12];
    const float* CW2 = (const float*)d_in[13];
    const float* Cb2 = (const float*)d_in[14];
    float* outp = (float*)d_out;

    const int E = in_sizes[0] / 2;
    const int N = in_sizes[4];
    const int B = out_size / NCLS;
    const int NB = (N + 255) / 256;     // scan blocks (must be <= 512)

    // ---- workspace layout (~118 MB; proven-safe budget >= 142 MB) ----
    char* w = (char*)d_ws;
    float*    xA         = (float*)w;   w += (size_t)N * HID * 4;     // 25.6M
    float*    xB         = (float*)w;   w += (size_t)N * HID * 4;     // 25.6M
    int*      eid_sorted = (int*)w;     w += (size_t)E * 4;           // 6.4M
    int*      src_sorted = (int*)w;     w += (size_t)E * 4;           // 6.4M
    int*      col_sorted = (int*)w;     w += (size_t)E * 4;           // 6.4M
    unsigned* pf_sorted  = (unsigned*)w; w += (size_t)E * 4;          // 6.4M
    int*      offs       = (int*)w;     w += (size_t)N * 4;
    int*      cursor     = (int*)w;     w += (size_t)N * 4;
    int*      loc        = (int*)w;     w += (size_t)N * 4;
    int*      part       = (int*)w;     w += 512 * 4;
    // zero region (single memset): hist, s, lsum, psum, pmax, pcnt
    char* zero_base = w;
    int*      hist  = (int*)w;          w += (size_t)N * 4;
    float*    s     = (float*)w;        w += (size_t)N * HID * 4;     // 25.6M
    float*    lsum  = (float*)w;        w += (size_t)N * IN_DIM * 4;  // 13.6M
    float*    psum  = (float*)w;        w += (size_t)B * HID * 4;
    unsigned* pmax  = (unsigned*)w;     w += (size_t)B * HID * 4;
    float*    pcnt  = (float*)w;        w += (size_t)B * 4;
    size_t zero_bytes = (size_t)(w - zero_base);

    hipMemsetAsync(zero_base, 0, zero_bytes, stream);

    // CSR build + bucket sort by col
    hist_pass<<<(E + 255) / 256, 256, 0, stream>>>(ei, hist, E);
    scan1<<<NB, 256, 0, stream>>>(hist, loc, part, N);
    scan2<<<1, 512, 0, stream>>>(part, NB);
    scan3<<<NB, 256, 0, stream>>>(loc, part, offs, cursor, N);
    sort_pass<<<(E + 255) / 256, 256, 0, stream>>>(
        ei, ports, flags, cursor, eid_sorted, src_sorted, col_sorted, pf_sorted, E);

    // edge-parallel MLP + segmented reduction -> s, lsum
    edge_mlp_reduce<<<(E + 127) / 128, 128, 0, stream>>>(
        eid_sorted, col_sorted, pf_sorted, eattr, emb_port, emb_flags,
        W1, b1, W2, b2, s, lsum, E);

    // self-loop MLP, finalize -> x1
    node_mlp<<<(N + 255) / 256, 256, 0, stream>>>(
        lsum, hist, W1, b1, W2, b2, s, xA, N);

    // layers 2 and 3
    gather_layer<<<(N + 3) / 4, 256, 0, stream>>>(
        offs, hist, src_sorted, xA, s, xB, N);
    gather_layer<<<(N + 3) / 4, 256, 0, stream>>>(
        offs, hist, src_sorted, xB, s, xA, N);

    // pooling + classifier
    pool_pass<<<((N + 63) / 64 * 64 + 255) / 256, 256, 0, stream>>>(
        xA, batch, psum, pmax, pcnt, N);
    classifier_pass<<<B, 64, 0, stream>>>(psum, pmax, pcnt, CW1, Cb1, CW2, Cb2, outp);
}